// Round 1
// baseline (663.219 us; speedup 1.0000x reference)
//
#include <hip/hip_runtime.h>
#include <stdint.h>

// ---------------------------------------------------------------------------
// Block-sparse MoE SwiGLU FFN (stk topology, balanced experts).
//   E=8, TOKENS=16384 (2048/expert), D=2048, HIDDEN=8192 (1024/expert)
//   out[e,t,:] = (silu(x_e w1_e^T) * (x_e w2_e^T)) @ w3_e
// Strategy: fp32 -> bf16 once per call, then two m97-style MFMA GEMMs
// (global_load_lds width-16 staging, 16x16x32 bf16 MFMA, 2-barrier K-loop).
// ---------------------------------------------------------------------------

#define NEXP   8
#define TOKENS 16384
#define D_IN   2048
#define HIDDEN 8192
#define T_E    2048   // tokens per expert
#define H_E    1024   // hidden per expert

typedef __attribute__((ext_vector_type(8))) __bf16 bf16x8;
typedef __attribute__((ext_vector_type(4))) float  f32x4;

__device__ __forceinline__ void async_ld16(const void* g, void* l) {
  __builtin_amdgcn_global_load_lds(
      (const __attribute__((address_space(1))) void*)g,
      (__attribute__((address_space(3))) void*)l, 16, 0, 0);
}

__device__ __forceinline__ unsigned short f2bf(float f) {
  union { float f; uint32_t u; } c; c.f = f;
  uint32_t u = c.u;
  u += 0x7FFFu + ((u >> 16) & 1u);   // round-to-nearest-even
  return (unsigned short)(u >> 16);
}

// ---------------- fp32 -> bf16 elementwise convert (4 elems/thread) --------
__global__ __launch_bounds__(256) void cvt_kernel(
    const float* __restrict__ in, unsigned short* __restrict__ out, int n4) {
  int i = blockIdx.x * 256 + threadIdx.x;
  if (i >= n4) return;
  float4 v = ((const float4*)in)[i];
  ushort4 r;
  r.x = f2bf(v.x); r.y = f2bf(v.y); r.z = f2bf(v.z); r.w = f2bf(v.w);
  ((ushort4*)out)[i] = r;
}

// ---------------- w3 [HIDDEN][D] fp32 -> w3t [E][D][H_E] bf16 --------------
__global__ __launch_bounds__(256) void transpose_w3_kernel(
    const float* __restrict__ w3, unsigned short* __restrict__ w3t) {
  __shared__ unsigned short tile[32][33];
  const int d0 = blockIdx.x * 32;   // 64 blocks along D
  const int h0 = blockIdx.y * 32;   // 256 blocks along HIDDEN
  const int tx = threadIdx.x;       // 0..31
  const int ty = threadIdx.y;       // 0..7
#pragma unroll
  for (int j = 0; j < 32; j += 8)
    tile[ty + j][tx] = f2bf(w3[(size_t)(h0 + ty + j) * D_IN + d0 + tx]);
  __syncthreads();
  const int e   = h0 >> 10;
  const int hl0 = h0 & 1023;
#pragma unroll
  for (int j = 0; j < 32; j += 8)
    w3t[((size_t)e * D_IN + d0 + ty + j) * H_E + hl0 + tx] = tile[tx][ty + j];
}

// ---------------- GEMM1 fused: h1 = x w1^T, h2 = x w2^T, g = silu(h1)*h2 ---
// block tile 128(M) x 64(N), BK=32; 4 waves in 2x2, each 64x32 per matrix.
__global__ __launch_bounds__(256) void gemm1_kernel(
    const unsigned short* __restrict__ xb,   // [E*T_E][D_IN] bf16
    const unsigned short* __restrict__ w1b,  // [HIDDEN][D_IN]
    const unsigned short* __restrict__ w2b,
    unsigned short* __restrict__ g)          // [E*T_E][H_E]
{
  __shared__ unsigned short As[128 * 32];
  __shared__ unsigned short B1s[64 * 32];
  __shared__ unsigned short B2s[64 * 32];

  const int bid = blockIdx.x;
  const int e   = bid >> 8;          // 256 blocks / expert
  const int t   = bid & 255;
  const int m0  = (t & 15) * 128;    // 16 M-tiles
  const int n0  = (t >> 4) * 64;     // 16 N-tiles

  const unsigned short* A  = xb  + (size_t)e * T_E * D_IN;
  const unsigned short* B1 = w1b + (size_t)e * H_E * D_IN;
  const unsigned short* B2 = w2b + (size_t)e * H_E * D_IN;

  const int tid  = threadIdx.x;
  const int wave = tid >> 6;
  const int lane = tid & 63;
  const int wm   = wave >> 1;        // 0..1 (64 rows)
  const int wn   = wave & 1;         // 0..1 (32 cols)
  const int srow = lane >> 2;        // staging: row within 16-row slab
  const int scol = (lane & 3) * 8;   // staging: bf16 col offset (16B chunks)
  const int lm   = lane & 15;
  const int q8   = (lane >> 4) * 8;

  f32x4 acc1[4][2], acc2[4][2];
#pragma unroll
  for (int mi = 0; mi < 4; ++mi)
#pragma unroll
    for (int ni = 0; ni < 2; ++ni) {
      acc1[mi][ni] = (f32x4){0.f, 0.f, 0.f, 0.f};
      acc2[mi][ni] = (f32x4){0.f, 0.f, 0.f, 0.f};
    }

  for (int k0 = 0; k0 < D_IN; k0 += 32) {
    __syncthreads();
    // A tile: 128x32 bf16 = 8 KB -> 2 wave-issues/wave
#pragma unroll
    for (int j = 0; j < 2; ++j) {
      int r = (wave * 2 + j) * 16 + srow;
      async_ld16(A + (size_t)(m0 + r) * D_IN + k0 + scol,
                 (char*)As + (wave * 2 + j) * 1024 + lane * 16);
    }
    // B1/B2 tiles: 64x32 = 4 KB -> 1 issue each
    {
      int r = wave * 16 + srow;
      async_ld16(B1 + (size_t)(n0 + r) * D_IN + k0 + scol,
                 (char*)B1s + wave * 1024 + lane * 16);
      async_ld16(B2 + (size_t)(n0 + r) * D_IN + k0 + scol,
                 (char*)B2s + wave * 1024 + lane * 16);
    }
    __syncthreads();

    bf16x8 af[4], b1f[2], b2f[2];
#pragma unroll
    for (int mi = 0; mi < 4; ++mi)
      af[mi] = *(const bf16x8*)(As + (wm * 64 + mi * 16 + lm) * 32 + q8);
#pragma unroll
    for (int ni = 0; ni < 2; ++ni) {
      b1f[ni] = *(const bf16x8*)(B1s + (wn * 32 + ni * 16 + lm) * 32 + q8);
      b2f[ni] = *(const bf16x8*)(B2s + (wn * 32 + ni * 16 + lm) * 32 + q8);
    }
#pragma unroll
    for (int mi = 0; mi < 4; ++mi)
#pragma unroll
      for (int ni = 0; ni < 2; ++ni) {
        acc1[mi][ni] = __builtin_amdgcn_mfma_f32_16x16x32_bf16(
            af[mi], b1f[ni], acc1[mi][ni], 0, 0, 0);
        acc2[mi][ni] = __builtin_amdgcn_mfma_f32_16x16x32_bf16(
            af[mi], b2f[ni], acc2[mi][ni], 0, 0, 0);
      }
  }

  // epilogue: g = silu(h1) * h2, bf16 store
  unsigned short* grow = g + (size_t)e * T_E * H_E;
  const int q4 = (lane >> 4) * 4;
#pragma unroll
  for (int mi = 0; mi < 4; ++mi)
#pragma unroll
    for (int ni = 0; ni < 2; ++ni)
#pragma unroll
      for (int r = 0; r < 4; ++r) {
        int row = m0 + wm * 64 + mi * 16 + q4 + r;
        int col = n0 + wn * 32 + ni * 16 + lm;
        float v1 = acc1[mi][ni][r];
        float v2 = acc2[mi][ni][r];
        float gv = (v1 / (1.0f + __expf(-v1))) * v2;
        grow[(size_t)row * H_E + col] = f2bf(gv);
      }
}

// ---------------- GEMM2: out = g @ w3t^T (per expert), fp32 out ------------
// block tile 128x128, BK=32; 4 waves in 2x2, each 64x64.
__global__ __launch_bounds__(256) void gemm2_kernel(
    const unsigned short* __restrict__ g,    // [E*T_E][H_E] bf16
    const unsigned short* __restrict__ w3t,  // [E][D_IN][H_E] bf16
    float* __restrict__ out)                 // [TOKENS][D_IN] fp32
{
  __shared__ unsigned short As[128 * 32];
  __shared__ unsigned short Bs[128 * 32];

  const int bid = blockIdx.x;
  const int e   = bid >> 8;          // 256 blocks / expert
  const int t   = bid & 255;
  const int m0  = (t & 15) * 128;    // 16 M-tiles (tokens)
  const int n0  = (t >> 4) * 128;    // 16 N-tiles (D)

  const unsigned short* A = g   + (size_t)e * T_E * H_E;   // ldA = H_E
  const unsigned short* B = w3t + (size_t)e * D_IN * H_E;  // ldB = H_E

  const int tid  = threadIdx.x;
  const int wave = tid >> 6;
  const int lane = tid & 63;
  const int wm   = wave >> 1;
  const int wn   = wave & 1;
  const int srow = lane >> 2;
  const int scol = (lane & 3) * 8;
  const int lm   = lane & 15;
  const int q8   = (lane >> 4) * 8;

  f32x4 acc[4][4];
#pragma unroll
  for (int mi = 0; mi < 4; ++mi)
#pragma unroll
    for (int ni = 0; ni < 4; ++ni) acc[mi][ni] = (f32x4){0.f, 0.f, 0.f, 0.f};

  for (int k0 = 0; k0 < H_E; k0 += 32) {
    __syncthreads();
#pragma unroll
    for (int j = 0; j < 2; ++j) {
      int r = (wave * 2 + j) * 16 + srow;
      async_ld16(A + (size_t)(m0 + r) * H_E + k0 + scol,
                 (char*)As + (wave * 2 + j) * 1024 + lane * 16);
      async_ld16(B + (size_t)(n0 + r) * H_E + k0 + scol,
                 (char*)Bs + (wave * 2 + j) * 1024 + lane * 16);
    }
    __syncthreads();

    bf16x8 af[4], bfr[4];
#pragma unroll
    for (int mi = 0; mi < 4; ++mi)
      af[mi] = *(const bf16x8*)(As + (wm * 64 + mi * 16 + lm) * 32 + q8);
#pragma unroll
    for (int ni = 0; ni < 4; ++ni)
      bfr[ni] = *(const bf16x8*)(Bs + (wn * 64 + ni * 16 + lm) * 32 + q8);
#pragma unroll
    for (int mi = 0; mi < 4; ++mi)
#pragma unroll
      for (int ni = 0; ni < 4; ++ni)
        acc[mi][ni] = __builtin_amdgcn_mfma_f32_16x16x32_bf16(
            af[mi], bfr[ni], acc[mi][ni], 0, 0, 0);
  }

  const int q4 = (lane >> 4) * 4;
  float* orow = out + (size_t)e * T_E * D_IN;
#pragma unroll
  for (int mi = 0; mi < 4; ++mi)
#pragma unroll
    for (int ni = 0; ni < 4; ++ni)
#pragma unroll
      for (int r = 0; r < 4; ++r) {
        int row = m0 + wm * 64 + mi * 16 + q4 + r;
        int col = n0 + wn * 64 + ni * 16 + lm;
        orow[(size_t)row * D_IN + col] = acc[mi][ni][r];
      }
}

// ---------------------------------------------------------------------------
extern "C" void kernel_launch(void* const* d_in, const int* in_sizes, int n_in,
                              void* d_out, int out_size, void* d_ws, size_t ws_size,
                              hipStream_t stream) {
  const float* x  = (const float*)d_in[0];   // [16384][2048]
  const float* w1 = (const float*)d_in[1];   // [8192][2048]
  const float* w2 = (const float*)d_in[2];
  const float* w3 = (const float*)d_in[3];
  float* out = (float*)d_out;

  // workspace layout (bytes)
  char* ws = (char*)d_ws;
  unsigned short* xb  = (unsigned short*)(ws);                       // 64 MB
  unsigned short* w1b = (unsigned short*)(ws + 67108864);            // 32 MB
  unsigned short* w2b = (unsigned short*)(ws + 100663296);           // 32 MB
  unsigned short* w3t = (unsigned short*)(ws + 134217728);           // 32 MB
  unsigned short* gbuf= (unsigned short*)(ws + 167772160);           // 32 MB

  // 1) convert x, w1, w2 to bf16
  cvt_kernel<<<(TOKENS * D_IN / 4 + 255) / 256, 256, 0, stream>>>(x, xb, TOKENS * D_IN / 4);
  cvt_kernel<<<(HIDDEN * D_IN / 4 + 255) / 256, 256, 0, stream>>>(w1, w1b, HIDDEN * D_IN / 4);
  cvt_kernel<<<(HIDDEN * D_IN / 4 + 255) / 256, 256, 0, stream>>>(w2, w2b, HIDDEN * D_IN / 4);

  // 2) transpose+convert w3 -> [E][D][H_E]
  transpose_w3_kernel<<<dim3(D_IN / 32, HIDDEN / 32), dim3(32, 8), 0, stream>>>(w3, w3t);

  // 3) fused sdd GEMMs + SiLU gate -> g (bf16)
  gemm1_kernel<<<NEXP * 256, 256, 0, stream>>>(xb, w1b, w2b, gbuf);

  // 4) dsd GEMM -> out (fp32)
  gemm2_kernel<<<NEXP * 256, 256, 0, stream>>>(gbuf, w3t, out);
}

// Round 2
// 657.239 us; speedup vs baseline: 1.0091x; 1.0091x over previous
//
#include <hip/hip_runtime.h>
#include <stdint.h>

// ---------------------------------------------------------------------------
// Block-sparse MoE SwiGLU FFN (stk topology, balanced experts).
//   E=8, TOKENS=16384 (2048/expert), D=2048, HIDDEN=8192 (1024/expert)
//   out[e,t,:] = (silu(x_e w1_e^T) * (x_e w2_e^T)) @ w3_e
// R1: m97-style MFMA GEMMs. R2: + expert->XCD affinity swizzle (bid&7) and
// 4x4 tile-group ordering for L2 locality (staging was L2-miss bound:
// 10 TB/s effective staging vs 26% MfmaUtil).
// ---------------------------------------------------------------------------

#define NEXP   8
#define TOKENS 16384
#define D_IN   2048
#define HIDDEN 8192
#define T_E    2048   // tokens per expert
#define H_E    1024   // hidden per expert

typedef __attribute__((ext_vector_type(8))) __bf16 bf16x8;
typedef __attribute__((ext_vector_type(4))) float  f32x4;

__device__ __forceinline__ void async_ld16(const void* g, void* l) {
  __builtin_amdgcn_global_load_lds(
      (const __attribute__((address_space(1))) void*)g,
      (__attribute__((address_space(3))) void*)l, 16, 0, 0);
}

__device__ __forceinline__ unsigned short f2bf(float f) {
  union { float f; uint32_t u; } c; c.f = f;
  uint32_t u = c.u;
  u += 0x7FFFu + ((u >> 16) & 1u);   // round-to-nearest-even
  return (unsigned short)(u >> 16);
}

// swizzled tile coords: s in [0,256) -> (mt, nt) in 16x16 tile grid,
// grouped 4x4 so 16 consecutive s share 4 row-tiles + 4 col-tiles (~L2-sized)
__device__ __forceinline__ void tile_swizzle(int s, int& mt, int& nt) {
  int g  = s >> 4;          // 16 groups
  int w  = s & 15;
  int gm = g & 3, gn = g >> 2;
  int wm = w & 3, wn = w >> 2;
  mt = gm * 4 + wm;
  nt = gn * 4 + wn;
}

// ---------------- fp32 -> bf16 elementwise convert (4 elems/thread) --------
__global__ __launch_bounds__(256) void cvt_kernel(
    const float* __restrict__ in, unsigned short* __restrict__ out, int n4) {
  int i = blockIdx.x * 256 + threadIdx.x;
  if (i >= n4) return;
  float4 v = ((const float4*)in)[i];
  ushort4 r;
  r.x = f2bf(v.x); r.y = f2bf(v.y); r.z = f2bf(v.z); r.w = f2bf(v.w);
  ((ushort4*)out)[i] = r;
}

// ---------------- w3 [HIDDEN][D] fp32 -> w3t [E][D][H_E] bf16 --------------
__global__ __launch_bounds__(256) void transpose_w3_kernel(
    const float* __restrict__ w3, unsigned short* __restrict__ w3t) {
  __shared__ unsigned short tile[32][33];
  const int d0 = blockIdx.x * 32;   // 64 blocks along D
  const int h0 = blockIdx.y * 32;   // 256 blocks along HIDDEN
  const int tx = threadIdx.x;       // 0..31
  const int ty = threadIdx.y;       // 0..7
#pragma unroll
  for (int j = 0; j < 32; j += 8)
    tile[ty + j][tx] = f2bf(w3[(size_t)(h0 + ty + j) * D_IN + d0 + tx]);
  __syncthreads();
  const int e   = h0 >> 10;
  const int hl0 = h0 & 1023;
#pragma unroll
  for (int j = 0; j < 32; j += 8)
    w3t[((size_t)e * D_IN + d0 + ty + j) * H_E + hl0 + tx] = tile[tx][ty + j];
}

// ---------------- GEMM1 fused: h1 = x w1^T, h2 = x w2^T, g = silu(h1)*h2 ---
// block tile 128(M) x 64(N), BK=32; 4 waves in 2x2, each 64x32 per matrix.
__global__ __launch_bounds__(256) void gemm1_kernel(
    const unsigned short* __restrict__ xb,   // [E*T_E][D_IN] bf16
    const unsigned short* __restrict__ w1b,  // [HIDDEN][D_IN]
    const unsigned short* __restrict__ w2b,
    unsigned short* __restrict__ g)          // [E*T_E][H_E]
{
  __shared__ unsigned short As[128 * 32];
  __shared__ unsigned short B1s[64 * 32];
  __shared__ unsigned short B2s[64 * 32];

  const int bid = blockIdx.x;
  const int e   = bid & 7;           // expert -> XCD affinity (round-robin)
  const int s   = bid >> 3;          // 256 tiles per expert
  int mt, nt;
  tile_swizzle(s, mt, nt);
  const int m0 = mt * 128;
  const int n0 = nt * 64;

  const unsigned short* A  = xb  + (size_t)e * T_E * D_IN;
  const unsigned short* B1 = w1b + (size_t)e * H_E * D_IN;
  const unsigned short* B2 = w2b + (size_t)e * H_E * D_IN;

  const int tid  = threadIdx.x;
  const int wave = tid >> 6;
  const int lane = tid & 63;
  const int wm   = wave >> 1;        // 0..1 (64 rows)
  const int wn   = wave & 1;         // 0..1 (32 cols)
  const int srow = lane >> 2;        // staging: row within 16-row slab
  const int scol = (lane & 3) * 8;   // staging: bf16 col offset (16B chunks)
  const int lm   = lane & 15;
  const int q8   = (lane >> 4) * 8;

  f32x4 acc1[4][2], acc2[4][2];
#pragma unroll
  for (int mi = 0; mi < 4; ++mi)
#pragma unroll
    for (int ni = 0; ni < 2; ++ni) {
      acc1[mi][ni] = (f32x4){0.f, 0.f, 0.f, 0.f};
      acc2[mi][ni] = (f32x4){0.f, 0.f, 0.f, 0.f};
    }

  for (int k0 = 0; k0 < D_IN; k0 += 32) {
    __syncthreads();
    // A tile: 128x32 bf16 = 8 KB -> 2 wave-issues/wave
#pragma unroll
    for (int j = 0; j < 2; ++j) {
      int r = (wave * 2 + j) * 16 + srow;
      async_ld16(A + (size_t)(m0 + r) * D_IN + k0 + scol,
                 (char*)As + (wave * 2 + j) * 1024 + lane * 16);
    }
    // B1/B2 tiles: 64x32 = 4 KB -> 1 issue each
    {
      int r = wave * 16 + srow;
      async_ld16(B1 + (size_t)(n0 + r) * D_IN + k0 + scol,
                 (char*)B1s + wave * 1024 + lane * 16);
      async_ld16(B2 + (size_t)(n0 + r) * D_IN + k0 + scol,
                 (char*)B2s + wave * 1024 + lane * 16);
    }
    __syncthreads();

    bf16x8 af[4], b1f[2], b2f[2];
#pragma unroll
    for (int mi = 0; mi < 4; ++mi)
      af[mi] = *(const bf16x8*)(As + (wm * 64 + mi * 16 + lm) * 32 + q8);
#pragma unroll
    for (int ni = 0; ni < 2; ++ni) {
      b1f[ni] = *(const bf16x8*)(B1s + (wn * 32 + ni * 16 + lm) * 32 + q8);
      b2f[ni] = *(const bf16x8*)(B2s + (wn * 32 + ni * 16 + lm) * 32 + q8);
    }
#pragma unroll
    for (int mi = 0; mi < 4; ++mi)
#pragma unroll
      for (int ni = 0; ni < 2; ++ni) {
        acc1[mi][ni] = __builtin_amdgcn_mfma_f32_16x16x32_bf16(
            af[mi], b1f[ni], acc1[mi][ni], 0, 0, 0);
        acc2[mi][ni] = __builtin_amdgcn_mfma_f32_16x16x32_bf16(
            af[mi], b2f[ni], acc2[mi][ni], 0, 0, 0);
      }
  }

  // epilogue: g = silu(h1) * h2, bf16 store
  unsigned short* grow = g + (size_t)e * T_E * H_E;
  const int q4 = (lane >> 4) * 4;
#pragma unroll
  for (int mi = 0; mi < 4; ++mi)
#pragma unroll
    for (int ni = 0; ni < 2; ++ni)
#pragma unroll
      for (int r = 0; r < 4; ++r) {
        int row = m0 + wm * 64 + mi * 16 + q4 + r;
        int col = n0 + wn * 32 + ni * 16 + lm;
        float v1 = acc1[mi][ni][r];
        float v2 = acc2[mi][ni][r];
        float gv = (v1 / (1.0f + __expf(-v1))) * v2;
        grow[(size_t)row * H_E + col] = f2bf(gv);
      }
}

// ---------------- GEMM2: out = g @ w3t^T (per expert), fp32 out ------------
// block tile 128x128, BK=32; 4 waves in 2x2, each 64x64.
__global__ __launch_bounds__(256) void gemm2_kernel(
    const unsigned short* __restrict__ g,    // [E*T_E][H_E] bf16
    const unsigned short* __restrict__ w3t,  // [E][D_IN][H_E] bf16
    float* __restrict__ out)                 // [TOKENS][D_IN] fp32
{
  __shared__ unsigned short As[128 * 32];
  __shared__ unsigned short Bs[128 * 32];

  const int bid = blockIdx.x;
  const int e   = bid & 7;           // expert -> XCD affinity
  const int s   = bid >> 3;
  int mt, nt;
  tile_swizzle(s, mt, nt);
  const int m0 = mt * 128;           // tokens
  const int n0 = nt * 128;           // D

  const unsigned short* A = g   + (size_t)e * T_E * H_E;   // ldA = H_E
  const unsigned short* B = w3t + (size_t)e * D_IN * H_E;  // ldB = H_E

  const int tid  = threadIdx.x;
  const int wave = tid >> 6;
  const int lane = tid & 63;
  const int wm   = wave >> 1;
  const int wn   = wave & 1;
  const int srow = lane >> 2;
  const int scol = (lane & 3) * 8;
  const int lm   = lane & 15;
  const int q8   = (lane >> 4) * 8;

  f32x4 acc[4][4];
#pragma unroll
  for (int mi = 0; mi < 4; ++mi)
#pragma unroll
    for (int ni = 0; ni < 4; ++ni) acc[mi][ni] = (f32x4){0.f, 0.f, 0.f, 0.f};

  for (int k0 = 0; k0 < H_E; k0 += 32) {
    __syncthreads();
#pragma unroll
    for (int j = 0; j < 2; ++j) {
      int r = (wave * 2 + j) * 16 + srow;
      async_ld16(A + (size_t)(m0 + r) * H_E + k0 + scol,
                 (char*)As + (wave * 2 + j) * 1024 + lane * 16);
      async_ld16(B + (size_t)(n0 + r) * H_E + k0 + scol,
                 (char*)Bs + (wave * 2 + j) * 1024 + lane * 16);
    }
    __syncthreads();

    bf16x8 af[4], bfr[4];
#pragma unroll
    for (int mi = 0; mi < 4; ++mi)
      af[mi] = *(const bf16x8*)(As + (wm * 64 + mi * 16 + lm) * 32 + q8);
#pragma unroll
    for (int ni = 0; ni < 4; ++ni)
      bfr[ni] = *(const bf16x8*)(Bs + (wn * 64 + ni * 16 + lm) * 32 + q8);
#pragma unroll
    for (int mi = 0; mi < 4; ++mi)
#pragma unroll
      for (int ni = 0; ni < 4; ++ni)
        acc[mi][ni] = __builtin_amdgcn_mfma_f32_16x16x32_bf16(
            af[mi], bfr[ni], acc[mi][ni], 0, 0, 0);
  }

  const int q4 = (lane >> 4) * 4;
  float* orow = out + (size_t)e * T_E * D_IN;
#pragma unroll
  for (int mi = 0; mi < 4; ++mi)
#pragma unroll
    for (int ni = 0; ni < 4; ++ni)
#pragma unroll
      for (int r = 0; r < 4; ++r) {
        int row = m0 + wm * 64 + mi * 16 + q4 + r;
        int col = n0 + wn * 64 + ni * 16 + lm;
        orow[(size_t)row * D_IN + col] = acc[mi][ni][r];
      }
}

// ---------------------------------------------------------------------------
extern "C" void kernel_launch(void* const* d_in, const int* in_sizes, int n_in,
                              void* d_out, int out_size, void* d_ws, size_t ws_size,
                              hipStream_t stream) {
  const float* x  = (const float*)d_in[0];   // [16384][2048]
  const float* w1 = (const float*)d_in[1];   // [8192][2048]
  const float* w2 = (const float*)d_in[2];
  const float* w3 = (const float*)d_in[3];
  float* out = (float*)d_out;

  // workspace layout (bytes)
  char* ws = (char*)d_ws;
  unsigned short* xb  = (unsigned short*)(ws);                       // 64 MB
  unsigned short* w1b = (unsigned short*)(ws + 67108864);            // 32 MB
  unsigned short* w2b = (unsigned short*)(ws + 100663296);           // 32 MB
  unsigned short* w3t = (unsigned short*)(ws + 134217728);           // 32 MB
  unsigned short* gbuf= (unsigned short*)(ws + 167772160);           // 32 MB

  // 1) convert x, w1, w2 to bf16
  cvt_kernel<<<(TOKENS * D_IN / 4 + 255) / 256, 256, 0, stream>>>(x, xb, TOKENS * D_IN / 4);
  cvt_kernel<<<(HIDDEN * D_IN / 4 + 255) / 256, 256, 0, stream>>>(w1, w1b, HIDDEN * D_IN / 4);
  cvt_kernel<<<(HIDDEN * D_IN / 4 + 255) / 256, 256, 0, stream>>>(w2, w2b, HIDDEN * D_IN / 4);

  // 2) transpose+convert w3 -> [E][D][H_E]
  transpose_w3_kernel<<<dim3(D_IN / 32, HIDDEN / 32), dim3(32, 8), 0, stream>>>(w3, w3t);

  // 3) fused sdd GEMMs + SiLU gate -> g (bf16)
  gemm1_kernel<<<NEXP * 256, 256, 0, stream>>>(xb, w1b, w2b, gbuf);

  // 4) dsd GEMM -> out (fp32)
  gemm2_kernel<<<NEXP * 256, 256, 0, stream>>>(gbuf, w3t, out);
}